// Round 3
// baseline (238.768 us; speedup 1.0000x reference)
//
#include <hip/hip_runtime.h>
#include <math.h>

#define BATCH 8
#define CH    256
#define H     128
#define W     128
#define HW    (H * W)          // 16384
#define OH    65
#define OW    65
#define NPIX  (OH * OW)        // 4225
#define CGRP  16               // channels per thread in pool kernel
#define PPR   33               // output-pixel pairs per row (65 -> 32 pairs + 1 single)
#define PAIRS (PPR * OH)       // 2145 pair-slots per (b, cg)

// Kernel 1: per-pixel channel L2 norm, float4-vectorized.
// Block = 256 threads = 4 waves covering 64 pixel-quads; wave wv sums channels
// [wv*64, wv*64+64); LDS-reduce the 4 partials. HBM-bound (~21 us).
__global__ __launch_bounds__(256) void norm_kernel(const float4* __restrict__ x4,
                                                   float4* __restrict__ n4) {
    __shared__ float4 part[4][64];
    const int lane = threadIdx.x & 63;
    const int wv   = threadIdx.x >> 6;
    const int q    = blockIdx.x * 64 + lane;   // global pixel-quad index
    const int b    = (q * 4) >> 14;            // / HW
    const int qin  = q - b * (HW / 4);         // quad within image

    const float4* p = x4 + (size_t)(b * CH + wv * 64) * (HW / 4) + qin;
    float4 acc = {0.f, 0.f, 0.f, 0.f};
    #pragma unroll 8
    for (int c = 0; c < 64; ++c) {
        float4 v = p[(size_t)c * (HW / 4)];
        acc.x += v.x * v.x; acc.y += v.y * v.y;
        acc.z += v.z * v.z; acc.w += v.w * v.w;
    }
    part[wv][lane] = acc;
    __syncthreads();
    if (wv == 0) {
        float4 a0 = part[0][lane], a1 = part[1][lane];
        float4 a2 = part[2][lane], a3 = part[3][lane];
        float4 r;
        r.x = sqrtf(a0.x + a1.x + a2.x + a3.x);
        r.y = sqrtf(a0.y + a1.y + a2.y + a3.y);
        r.z = sqrtf(a0.z + a1.z + a2.z + a3.z);
        r.w = sqrtf(a0.w + a1.w + a2.w + a3.w);
        n4[q] = r;
    }
}

// Kernel 2: softmax-weighted 3x3 stride-2 pooling, one thread = a PAIR of
// horizontally-adjacent output pixels (ow0, ow0+1). Their windows span 5 input
// columns [iw0, iw0+4], iw0 = 4*pc-2 (even): 3 loads/row (f2,f2,scalar) serve
// both outputs. OOB handled by clamped in-buffer addresses + exact-zero weights.
__global__ __launch_bounds__(256) void pool_kernel(const float* __restrict__ x,
                                                   const float* __restrict__ n,
                                                   float* __restrict__ out) {
    int pw = blockIdx.x * blockDim.x + threadIdx.x;
    if (pw >= PAIRS) return;
    const int b  = blockIdx.y;
    const int cg = blockIdx.z;
    const int oh = pw / PPR;
    const int pc = pw - oh * PPR;
    const int ow0 = pc * 2;
    const bool has2 = (ow0 + 1) < OW;
    const int iw0 = ow0 * 2 - 2;               // even, in [-2, 126]

    const float* nb = n + b * HW;

    // 3x5 norm neighborhood (OOB -> 0, matching reference's zero-padded norm)
    float nvv[3][5];
    bool  vld[3][5];
    int offa[3], offb[3], offc[3];
    #pragma unroll
    for (int r = 0; r < 3; ++r) {
        int ih = oh * 2 + r - 2;
        bool vh = (unsigned)ih < (unsigned)H;
        int ihc = ih < 0 ? 0 : (ih > H - 1 ? H - 1 : ih);
        int rb = ihc * W;
        #pragma unroll
        for (int c = 0; c < 5; ++c) {
            int iw = iw0 + c;
            bool v = vh && ((unsigned)iw < (unsigned)W);
            int iwc = iw < 0 ? 0 : (iw > W - 1 ? W - 1 : iw);
            vld[r][c] = v;
            nvv[r][c] = v ? nb[rb + iwc] : 0.0f;
        }
        int acol = iw0 < 0 ? 0 : iw0;                        // even -> 8B aligned
        int bcol = (iw0 + 2) > (W - 2) ? (W - 2) : (iw0 + 2);
        int ccol = (iw0 + 4) > (W - 1) ? (W - 1) : (iw0 + 4);
        offa[r] = rb + acol; offb[r] = rb + bcol; offc[r] = rb + ccol;
    }

    // softmax over window positions for each of the two outputs
    float m0 = 0.f, m1 = 0.f;   // OOB positions carry n=0 -> max starts at 0
    #pragma unroll
    for (int r = 0; r < 3; ++r) {
        m0 = fmaxf(m0, fmaxf(fmaxf(nvv[r][0], nvv[r][1]), nvv[r][2]));
        m1 = fmaxf(m1, fmaxf(fmaxf(nvv[r][2], nvv[r][3]), nvv[r][4]));
    }
    float w0[9], w1[9];
    float d0 = 0.f, d1 = 0.f;
    #pragma unroll
    for (int r = 0; r < 3; ++r) {
        #pragma unroll
        for (int c = 0; c < 3; ++c) {
            float e0 = __expf(nvv[r][c] - m0);       // OOB -> exp(0-m) in denom
            d0 += e0;
            w0[r * 3 + c] = vld[r][c] ? e0 : 0.0f;   // weight 0 in numerator
            float e1 = __expf(nvv[r][c + 2] - m1);
            d1 += e1;
            w1[r * 3 + c] = vld[r][c + 2] ? e1 : 0.0f;
        }
    }
    float i0 = 1.0f / d0, i1 = 1.0f / d1;
    #pragma unroll
    for (int k = 0; k < 9; ++k) { w0[k] *= i0; w1[k] *= i1; }

    const float* xb = x + (size_t)(b * CH + cg * CGRP) * HW;
    float*       ob = out + (size_t)(b * CH + cg * CGRP) * NPIX + oh * OW + ow0;

    #pragma unroll 4
    for (int c = 0; c < CGRP; ++c) {
        const float* xc = xb + (size_t)c * HW;
        float a0 = 0.f, a1 = 0.f;
        #pragma unroll
        for (int r = 0; r < 3; ++r) {
            float2 va = *(const float2*)(xc + offa[r]);  // cols iw0, iw0+1
            float2 vb = *(const float2*)(xc + offb[r]);  // cols iw0+2, iw0+3
            float  vc = xc[offc[r]];                     // col  iw0+4
            a0 += w0[r * 3 + 0] * va.x + w0[r * 3 + 1] * va.y + w0[r * 3 + 2] * vb.x;
            a1 += w1[r * 3 + 0] * vb.x + w1[r * 3 + 1] * vb.y + w1[r * 3 + 2] * vc;
        }
        ob[(size_t)c * NPIX] = a0;
        if (has2) ob[(size_t)c * NPIX + 1] = a1;
    }
}

extern "C" void kernel_launch(void* const* d_in, const int* in_sizes, int n_in,
                              void* d_out, int out_size, void* d_ws, size_t ws_size,
                              hipStream_t stream) {
    const float* x = (const float*)d_in[0];
    float* out = (float*)d_out;
    float* nbuf = (float*)d_ws;  // BATCH*H*W floats = 512 KB

    norm_kernel<<<512, 256, 0, stream>>>((const float4*)x, (float4*)nbuf);

    dim3 grid((PAIRS + 255) / 256, BATCH, CH / CGRP);
    pool_kernel<<<grid, 256, 0, stream>>>(x, nbuf, out);
}